// Round 2
// baseline (1715.584 us; speedup 1.0000x reference)
//
#include <hip/hip_runtime.h>

// GAT, 5 layers, N=100000 nodes, F_IN=602, H=41 heads, C=1, E=1.6M (+N self-loops).
// CSR by dst built once per call; per layer: h = in @ W (fp32 vector GEMM), then one
// thread per (node,head) computes segment softmax + max-aggregation in ONE pass using
// the self-loop logit as a fixed softmax reference (no online max needed: logits are
// O(1) because weights are scaled x0.1; exp(e - e0) cannot overflow).
// All exp in log2 domain: leaky_relu commutes with positive scaling, and
// leaky(x) = max(x, 0.2x), so the whole logit pipeline is fma+mul+max+sub+v_exp.

#define N_NODES 100000
#define F_IN    602
#define NH      41          // H*C
#define NEDGE   1600000
#define NLAYERS 5
#define LOG2E   1.44269504088896340736f

// ------------------------- CSR build -------------------------
__global__ void hist_kernel(const int* __restrict__ dst, int* __restrict__ cnt, int e) {
    int i = blockIdx.x * blockDim.x + threadIdx.x;
    if (i < e) atomicAdd(&cnt[dst[i]], 1);
}

__global__ __launch_bounds__(1024) void scan_kernel(const int* __restrict__ cnt,
                                                    int* __restrict__ row_ptr, int n) {
    __shared__ int sums[1024];
    int t = threadIdx.x;
    int chunk = (n + 1023) >> 10;           // 98
    int start = t * chunk;
    int end   = min(start + chunk, n);
    int s = 0;
    for (int i = start; i < end; ++i) s += cnt[i];
    sums[t] = s;
    __syncthreads();
    // Hillis-Steele inclusive scan over 1024 partials
    for (int off = 1; off < 1024; off <<= 1) {
        int v = (t >= off) ? sums[t - off] : 0;
        __syncthreads();
        sums[t] += v;
        __syncthreads();
    }
    int run = (t == 0) ? 0 : sums[t - 1];   // exclusive base for this chunk
    for (int i = start; i < end; ++i) { row_ptr[i] = run; run += cnt[i]; }
    if (start < n && end == n) row_ptr[n] = run;
}

__global__ void scatter_kernel(const int* __restrict__ src, const int* __restrict__ dst,
                               const int* __restrict__ row_ptr, int* __restrict__ cur,
                               int* __restrict__ esrc, int e) {
    int i = blockIdx.x * blockDim.x + threadIdx.x;
    if (i < e) {
        int d = dst[i];
        int pos = row_ptr[d] + atomicAdd(&cur[d], 1);
        esrc[pos] = src[i];
    }
}

// ------------------------- layer-0 GEMM: [N,602] @ [602,41] -------------------------
__global__ __launch_bounds__(256) void gemm0_kernel(const float* __restrict__ x,
                                                    const float* __restrict__ w,
                                                    float* __restrict__ h) {
    __shared__ float xs[32][257];           // [k][row], padded: conflict-free reads
    int tid  = threadIdx.x;
    int row0 = blockIdx.x * 256;
    int row  = row0 + tid;

    float acc[NH];
#pragma unroll
    for (int c = 0; c < NH; ++c) acc[c] = 0.f;

    const int NCH = F_IN / 32;              // 18 full chunks
    const int REM = F_IN - NCH * 32;        // 26

    for (int ci = 0; ci < NCH; ++ci) {
        int k0 = ci * 32;
        // cooperative coalesced load of 256 rows x 32 k, transposed into LDS
#pragma unroll
        for (int li = 0; li < 32; ++li) {
            int g  = li * 256 + tid;
            int kk = g & 31;
            int r  = g >> 5;
            int rr = row0 + r;
            xs[kk][r] = (rr < N_NODES) ? x[rr * F_IN + k0 + kk] : 0.f;
        }
        __syncthreads();
#pragma unroll 4
        for (int kk = 0; kk < 32; ++kk) {
            float xv = xs[kk][tid];
#pragma unroll
            for (int c = 0; c < NH; ++c)
                acc[c] = fmaf(xv, w[(k0 + kk) * NH + c], acc[c]);  // w idx wave-uniform -> s_load
        }
        __syncthreads();
    }
    {   // remainder chunk of 26
        int k0 = NCH * 32;
#pragma unroll
        for (int li = 0; li < 32; ++li) {
            int g  = li * 256 + tid;
            int kk = g & 31;
            int r  = g >> 5;
            int rr = row0 + r;
            xs[kk][r] = (kk < REM && rr < N_NODES) ? x[rr * F_IN + k0 + kk] : 0.f;
        }
        __syncthreads();
#pragma unroll 2
        for (int kk = 0; kk < REM; ++kk) {
            float xv = xs[kk][tid];
#pragma unroll
            for (int c = 0; c < NH; ++c)
                acc[c] = fmaf(xv, w[(k0 + kk) * NH + c], acc[c]);
        }
        __syncthreads();
    }

    if (row < N_NODES) {
#pragma unroll
        for (int c = 0; c < NH; ++c) h[row * NH + c] = acc[c];
    }
}

// ------------------------- small GEMM: [N,41] @ [41,41] -------------------------
__global__ __launch_bounds__(256) void gemm_small_kernel(const float* __restrict__ in,
                                                         const float* __restrict__ w,
                                                         float* __restrict__ h) {
    int row = blockIdx.x * 256 + threadIdx.x;
    if (row >= N_NODES) return;
    float r[NH];
#pragma unroll
    for (int k = 0; k < NH; ++k) r[k] = in[row * NH + k];   // row -> regs once
    float acc[NH];
#pragma unroll
    for (int c = 0; c < NH; ++c) acc[c] = 0.f;
#pragma unroll 1
    for (int k = 0; k < NH; ++k) {          // runtime k: w idx wave-uniform -> s_load
        float xv = r[k];
#pragma unroll
        for (int c = 0; c < NH; ++c)
            acc[c] = fmaf(xv, w[k * NH + c], acc[c]);
    }
#pragma unroll
    for (int c = 0; c < NH; ++c) h[row * NH + c] = acc[c];
}

// ------------------------- GAT aggregation: one thread per (node, head) -------------------------
// alpha_e = exp(e_e - e_self) / sum_e exp(e_e - e_self)   (identical to softmax w/ max-shift;
// safe: logits are O(1)).  out = relu( max_e(alpha_e * h_src_e) + bias ).
// log2 domain: leaky(x)=max(x,0.2x) commutes with the positive log2(e) scale, and
// v_exp_f32 is exp2 natively.
__global__ __launch_bounds__(256) void gat_kernel(const float* __restrict__ h,
                                                  const int* __restrict__ row_ptr,
                                                  const int* __restrict__ esrc,
                                                  const float* __restrict__ att_s,
                                                  const float* __restrict__ att_d,
                                                  const float* __restrict__ bias,
                                                  float* __restrict__ out,
                                                  int apply_relu) {
    int idx = blockIdx.x * blockDim.x + threadIdx.x;
    if (idx >= N_NODES * NH) return;
    int n  = idx / NH;
    int hd = idx - n * NH;

    float as2 = att_s[hd] * LOG2E;                   // fold log2(e) into the coeffs
    float hn  = h[idx];                              // h[n*NH+hd]
    float adt2 = hn * att_d[hd] * LOG2E;

    // self-loop logit (log2 domain) = fixed softmax reference
    float t0 = fmaf(hn, as2, adt2);
    float e0 = fmaxf(t0, 0.2f * t0);                 // leaky_relu
    float den = 1.0f;                                // exp2(e0-e0)
    float num = hn;                                  // 1 * h[n]

    int s = row_ptr[n], t = row_ptr[n + 1];
    for (int j = s; j < t; ++j) {
        int   sr = esrc[j];                          // same addr across the 41 head-lanes
        float hs = h[__mul24(sr, NH) + hd];          // coalesced 164B row gather
        float tt = fmaf(hs, as2, adt2);
        float ee = fmaxf(tt, 0.2f * tt);             // leaky_relu (log2 domain)
        float p  = __builtin_amdgcn_exp2f(ee - e0);  // exp(e - e_self), bounded
        den += p;
        num = fmaxf(num, p * hs);
    }
    float o = num / den + bias[hd];
    out[idx] = apply_relu ? fmaxf(o, 0.f) : o;
}

// ------------------------- final log_softmax over 41 classes -------------------------
__global__ __launch_bounds__(256) void logsoftmax_kernel(const float* __restrict__ in,
                                                         float* __restrict__ out) {
    int n = blockIdx.x * blockDim.x + threadIdx.x;
    if (n >= N_NODES) return;
    float v[NH];
#pragma unroll
    for (int c = 0; c < NH; ++c) v[c] = in[n * NH + c];
    float m = v[0];
#pragma unroll
    for (int c = 1; c < NH; ++c) m = fmaxf(m, v[c]);
    float ssum = 0.f;
#pragma unroll
    for (int c = 0; c < NH; ++c) ssum += __expf(v[c] - m);
    float lg = m + logf(ssum);
#pragma unroll
    for (int c = 0; c < NH; ++c) out[n * NH + c] = v[c] - lg;
}

// ------------------------- launch -------------------------
extern "C" void kernel_launch(void* const* d_in, const int* in_sizes, int n_in,
                              void* d_out, int out_size, void* d_ws, size_t ws_size,
                              hipStream_t stream) {
    const float* x   = (const float*)d_in[0];   // [N, 602]
    const int*   ei  = (const int*)  d_in[1];   // [2, E]
    const float* W0  = (const float*)d_in[2];   // [602, 41]
    const float* Wr  = (const float*)d_in[3];   // [4, 41, 41]
    const float* as_ = (const float*)d_in[4];   // [5, 41]
    const float* ad_ = (const float*)d_in[5];   // [5, 41]
    const float* bs  = (const float*)d_in[6];   // [5, 41]
    float* out = (float*)d_out;                 // [N, 41]

    const int* src = ei;
    const int* dst = ei + NEDGE;

    char* ws = (char*)d_ws;
    size_t off = 0;
    auto alloc = [&](size_t bytes) -> void* {
        void* p = ws + off;
        off += (bytes + 255) & ~size_t(255);
        return p;
    };
    int*   cnt     = (int*)  alloc((size_t)N_NODES * 4);
    int*   row_ptr = (int*)  alloc((size_t)(N_NODES + 1) * 4);
    int*   esrc    = (int*)  alloc((size_t)NEDGE * 4);
    float* hbuf    = (float*)alloc((size_t)N_NODES * NH * 4);
    float* obuf    = (float*)alloc((size_t)N_NODES * NH * 4);

    // CSR build (per call: harness re-poisons ws, so cnt must be zeroed here)
    hipMemsetAsync(cnt, 0, (size_t)N_NODES * 4, stream);
    hist_kernel<<<(NEDGE + 255) / 256, 256, 0, stream>>>(dst, cnt, NEDGE);
    scan_kernel<<<1, 1024, 0, stream>>>(cnt, row_ptr, N_NODES);
    hipMemsetAsync(cnt, 0, (size_t)N_NODES * 4, stream);
    scatter_kernel<<<(NEDGE + 255) / 256, 256, 0, stream>>>(src, dst, row_ptr, cnt, esrc, NEDGE);

    // layer 0 GEMM
    gemm0_kernel<<<(N_NODES + 255) / 256, 256, 0, stream>>>(x, W0, hbuf);

    for (int l = 0; l < NLAYERS; ++l) {
        if (l > 0)
            gemm_small_kernel<<<(N_NODES + 255) / 256, 256, 0, stream>>>(
                obuf, Wr + (size_t)(l - 1) * NH * NH, hbuf);
        gat_kernel<<<(N_NODES * NH + 255) / 256, 256, 0, stream>>>(
            hbuf, row_ptr, esrc, as_ + l * NH, ad_ + l * NH, bs + l * NH,
            obuf, (l < NLAYERS - 1) ? 1 : 0);
    }

    logsoftmax_kernel<<<(N_NODES + 255) / 256, 256, 0, stream>>>(obuf, out);
}

// Round 4
// 1471.276 us; speedup vs baseline: 1.1661x; 1.1661x over previous
//
#include <hip/hip_runtime.h>

// GAT, 5 layers, N=100000, F_IN=602, H=41 heads, C=1, E=1.6M (+N self-loops).
// CSR by dst built once per call. Per layer: h = in @ W (fp32), then one thread per
// (node,head) does single-pass segment softmax + max-aggregation using the self-loop
// logit as fixed softmax reference (logits are O(1): weights scaled x0.1).
// exp in log2 domain (v_exp_f32 is exp2); leaky_relu commutes with positive scale.
// W pre-transposed to [col][k]; weight bases readfirstlane'd -> s_load scalar reads.

#define N_NODES 100000
#define F_IN    602
#define NH      41
#define NEDGE   1600000
#define NLAYERS 5
#define LOG2E   1.44269504088896340736f

// ------------------------- CSR build -------------------------
__global__ void hist_kernel(const int* __restrict__ dst, int* __restrict__ cnt, int e) {
    int i = blockIdx.x * blockDim.x + threadIdx.x;
    if (i < e) atomicAdd(&cnt[dst[i]], 1);
}

__global__ __launch_bounds__(1024) void scan_kernel(const int* __restrict__ cnt,
                                                    int* __restrict__ row_ptr, int n) {
    __shared__ int sums[1024];
    int t = threadIdx.x;
    int chunk = (n + 1023) >> 10;
    int start = t * chunk;
    int end   = min(start + chunk, n);
    int s = 0;
    for (int i = start; i < end; ++i) s += cnt[i];
    sums[t] = s;
    __syncthreads();
    for (int off = 1; off < 1024; off <<= 1) {
        int v = (t >= off) ? sums[t - off] : 0;
        __syncthreads();
        sums[t] += v;
        __syncthreads();
    }
    int run = (t == 0) ? 0 : sums[t - 1];
    for (int i = start; i < end; ++i) { row_ptr[i] = run; run += cnt[i]; }
    if (start < n && end == n) row_ptr[n] = run;
}

__global__ void scatter_kernel(const int* __restrict__ src, const int* __restrict__ dst,
                               const int* __restrict__ row_ptr, int* __restrict__ cur,
                               int* __restrict__ esrc, int e) {
    int i = blockIdx.x * blockDim.x + threadIdx.x;
    if (i < e) {
        int d = dst[i];
        int pos = row_ptr[d] + atomicAdd(&cur[d], 1);
        esrc[pos] = src[i];
    }
}

// ------------------------- W transpose (once per call, tiny) -------------------------
__global__ void transpose_w_kernel(const float* __restrict__ W0, const float* __restrict__ Wr,
                                   float* __restrict__ wT0, float* __restrict__ wTr) {
    int i = blockIdx.x * blockDim.x + threadIdx.x;
    if (i < F_IN * NH) {                       // W0 [602][41] -> wT0 [41][602]
        int k = i / NH, c = i - k * NH;
        wT0[c * F_IN + k] = W0[i];
    }
    if (i < 4 * NH * NH) {                     // Wr [4][41][41] -> wTr [4][41(col)][41(k)]
        int l = i / (NH * NH), rem = i - l * NH * NH;
        int k = rem / NH, c = rem - k * NH;
        wTr[l * NH * NH + c * NH + k] = Wr[i];
    }
}

// ------------------------- layer-0 GEMM: [N,602] @ [602,41] -------------------------
// 256 thr = 4 waves; 64 rows/block; wave q -> cols [cbase, cbase+10], cbase=min(11q,30)
// (overlap benign: identical values). x tile [32k][64r] double-buffered in LDS
// (reg-staged, 1 barrier/chunk). wT base readfirstlane'd -> scalar s_load runs.
__global__ __launch_bounds__(256) void gemm0_kernel(const float* __restrict__ x,
                                                    const float* __restrict__ wT,
                                                    float* __restrict__ h) {
    __shared__ float xs[2][32][65];            // [buf][k][row], pad: conflict-free
    const int tid  = threadIdx.x;
    const int q    = tid >> 6;                 // wave id = col group
    const int r    = tid & 63;                 // row within block (compute)
    const int rr   = tid >> 5;                 // staging helpers
    const int kk   = tid & 31;
    const int row0 = blockIdx.x * 64;
    const int cbase = __builtin_amdgcn_readfirstlane(min(q * 11, NH - 11));
    const float* __restrict__ wq = wT + cbase * F_IN;   // SGPR base -> s_load
    const int NCHT = 19;                       // 18x32 + 26

    float acc[11];
#pragma unroll
    for (int c = 0; c < 11; ++c) acc[c] = 0.f;
    float rg[8];

    auto stage_load = [&](int ci) {
        int k0 = ci * 32;
        int kl = (ci == 18) ? 26 : 32;
#pragma unroll
        for (int li = 0; li < 8; ++li) {
            int rrow = row0 + li * 8 + rr;
            rg[li] = (kk < kl && rrow < N_NODES) ? x[rrow * F_IN + k0 + kk] : 0.f;
        }
    };
    auto stage_write = [&](int b) {
#pragma unroll
        for (int li = 0; li < 8; ++li) xs[b][kk][li * 8 + rr] = rg[li];
    };

    stage_load(0);
    stage_write(0);

    for (int ci = 0; ci < NCHT; ++ci) {
        if (ci + 1 < NCHT) stage_load(ci + 1);          // global->reg under compute
        __syncthreads();                                 // prev stage_write visible
        const int b = ci & 1, k0 = ci * 32;
        if (ci < 18) {
#pragma unroll
            for (int k = 0; k < 32; ++k) {
                float xv = xs[b][k][r];
#pragma unroll
                for (int c = 0; c < 11; ++c)
                    acc[c] = fmaf(xv, wq[c * F_IN + k0 + k], acc[c]);
            }
        } else {
#pragma unroll
            for (int k = 0; k < 26; ++k) {
                float xv = xs[b][k][r];
#pragma unroll
                for (int c = 0; c < 11; ++c)
                    acc[c] = fmaf(xv, wq[c * F_IN + k0 + k], acc[c]);
            }
        }
        if (ci + 1 < NCHT) stage_write((ci + 1) & 1);   // safe: all left that buf at sync
    }

    int row = row0 + r;
    if (row < N_NODES) {
#pragma unroll
        for (int c = 0; c < 11; ++c)
            h[row * NH + cbase + c] = acc[c];
    }
}

// ------------------------- small GEMM: [N,41] @ [41,41] -------------------------
__global__ __launch_bounds__(256) void gemm_small_kernel(const float* __restrict__ in,
                                                         const float* __restrict__ wT,
                                                         float* __restrict__ h) {
    __shared__ float xs[NH][65];               // [k][row]
    const int tid  = threadIdx.x;
    const int q    = tid >> 6;
    const int r    = tid & 63;
    const int row0 = blockIdx.x * 64;
    const int cbase = __builtin_amdgcn_readfirstlane(min(q * 11, NH - 11));
    const float* __restrict__ wq = wT + cbase * NH;     // SGPR base -> s_load

    const int base = row0 * NH;
    for (int e = tid; e < 64 * NH; e += 256) { // fully coalesced linear read
        int rrw = e / NH;
        int k   = e - rrw * NH;
        xs[k][rrw] = (row0 + rrw < N_NODES) ? in[base + e] : 0.f;
    }
    __syncthreads();

    float acc[11];
#pragma unroll
    for (int c = 0; c < 11; ++c) acc[c] = 0.f;
#pragma unroll
    for (int k = 0; k < NH; ++k) {
        float xv = xs[k][r];
#pragma unroll
        for (int c = 0; c < 11; ++c)
            acc[c] = fmaf(xv, wq[c * NH + k], acc[c]);
    }

    int row = row0 + r;
    if (row < N_NODES) {
#pragma unroll
        for (int c = 0; c < 11; ++c)
            h[row * NH + cbase + c] = acc[c];
    }
}

// ------------------------- GAT aggregation: thread per (node, head) -------------------------
// Depth-3 software pipeline on the esrc->h dependent-load chain; esrc has 4 sentinel
// slots so j+2 accesses never branch. Self-loop handled analytically as init.
__global__ __launch_bounds__(256) void gat_kernel(const float* __restrict__ h,
                                                  const int* __restrict__ row_ptr,
                                                  const int* __restrict__ esrc,
                                                  const float* __restrict__ att_s,
                                                  const float* __restrict__ att_d,
                                                  const float* __restrict__ bias,
                                                  float* __restrict__ out,
                                                  int apply_relu) {
    int idx = blockIdx.x * blockDim.x + threadIdx.x;
    if (idx >= N_NODES * NH) return;
    int n  = idx / NH;
    int hd = idx - n * NH;

    float as2  = att_s[hd] * LOG2E;
    float hn   = h[idx];
    float adt2 = hn * att_d[hd] * LOG2E;

    float t0 = fmaf(hn, as2, adt2);
    float e0 = fmaxf(t0, 0.2f * t0);           // leaky_relu, log2 domain
    float den = 1.0f;                          // self-loop: exp2(e0-e0)
    float num = hn;

    int s = row_ptr[n], t = row_ptr[n + 1];
    int   sra = esrc[s];                       // sentinel slots make these in-bounds
    int   srb = esrc[s + 1];
    float hsa = h[__mul24(sra, NH) + hd];
    float hsb = h[__mul24(srb, NH) + hd];
    for (int j = s; j < t; ++j) {
        int   src2 = esrc[j + 2];              // 2 iterations ahead
        float hsc  = h[__mul24(src2, NH) + hd];
        float tt = fmaf(hsa, as2, adt2);
        float ee = fmaxf(tt, 0.2f * tt);
        float p  = __builtin_amdgcn_exp2f(ee - e0);
        den += p;
        num = fmaxf(num, p * hsa);
        hsa = hsb; hsb = hsc;
    }
    float o = num / den + bias[hd];
    out[idx] = apply_relu ? fmaxf(o, 0.f) : o;
}

// ------------------------- final log_softmax over 41 classes -------------------------
__global__ __launch_bounds__(256) void logsoftmax_kernel(const float* __restrict__ in,
                                                         float* __restrict__ out) {
    int n = blockIdx.x * blockDim.x + threadIdx.x;
    if (n >= N_NODES) return;
    float v[NH];
#pragma unroll
    for (int c = 0; c < NH; ++c) v[c] = in[n * NH + c];
    float m = v[0];
#pragma unroll
    for (int c = 1; c < NH; ++c) m = fmaxf(m, v[c]);
    float ssum = 0.f;
#pragma unroll
    for (int c = 0; c < NH; ++c) ssum += __expf(v[c] - m);
    float lg = m + logf(ssum);
#pragma unroll
    for (int c = 0; c < NH; ++c) out[n * NH + c] = v[c] - lg;
}

// ------------------------- launch -------------------------
extern "C" void kernel_launch(void* const* d_in, const int* in_sizes, int n_in,
                              void* d_out, int out_size, void* d_ws, size_t ws_size,
                              hipStream_t stream) {
    const float* x   = (const float*)d_in[0];
    const int*   ei  = (const int*)  d_in[1];
    const float* W0  = (const float*)d_in[2];
    const float* Wr  = (const float*)d_in[3];
    const float* as_ = (const float*)d_in[4];
    const float* ad_ = (const float*)d_in[5];
    const float* bs  = (const float*)d_in[6];
    float* out = (float*)d_out;

    const int* src = ei;
    const int* dst = ei + NEDGE;

    char* ws = (char*)d_ws;
    size_t off = 0;
    auto alloc = [&](size_t bytes) -> void* {
        void* p = ws + off;
        off += (bytes + 255) & ~size_t(255);
        return p;
    };
    int*   cnt     = (int*)  alloc((size_t)N_NODES * 4);
    int*   row_ptr = (int*)  alloc((size_t)(N_NODES + 1) * 4);
    int*   esrc    = (int*)  alloc((size_t)(NEDGE + 4) * 4);
    float* hbuf    = (float*)alloc((size_t)N_NODES * NH * 4);
    float* obuf    = (float*)alloc((size_t)N_NODES * NH * 4);
    float* wT0     = (float*)alloc((size_t)NH * F_IN * 4);
    float* wTr     = (float*)alloc((size_t)4 * NH * NH * 4);

    // CSR build
    hipMemsetAsync(cnt, 0, (size_t)N_NODES * 4, stream);
    hipMemsetAsync(esrc + NEDGE, 0, 16, stream);         // prefetch sentinels
    hist_kernel<<<(NEDGE + 255) / 256, 256, 0, stream>>>(dst, cnt, NEDGE);
    scan_kernel<<<1, 1024, 0, stream>>>(cnt, row_ptr, N_NODES);
    hipMemsetAsync(cnt, 0, (size_t)N_NODES * 4, stream);
    scatter_kernel<<<(NEDGE + 255) / 256, 256, 0, stream>>>(src, dst, row_ptr, cnt, esrc, NEDGE);

    // W transpose (tiny)
    transpose_w_kernel<<<(F_IN * NH + 255) / 256, 256, 0, stream>>>(W0, Wr, wT0, wTr);

    const int NBLK = (N_NODES + 63) / 64;                // 1563
    gemm0_kernel<<<NBLK, 256, 0, stream>>>(x, wT0, hbuf);

    for (int l = 0; l < NLAYERS; ++l) {
        if (l > 0)
            gemm_small_kernel<<<NBLK, 256, 0, stream>>>(
                obuf, wTr + (size_t)(l - 1) * NH * NH, hbuf);
        gat_kernel<<<(N_NODES * NH + 255) / 256, 256, 0, stream>>>(
            hbuf, row_ptr, esrc, as_ + l * NH, ad_ + l * NH, bs + l * NH,
            obuf, (l < NLAYERS - 1) ? 1 : 0);
    }

    logsoftmax_kernel<<<(N_NODES + 255) / 256, 256, 0, stream>>>(obuf, out);
}